// Round 1
// baseline (2790.554 us; speedup 1.0000x reference)
//
#include <hip/hip_runtime.h>
#include <math.h>

#define HIDDEN 2048
#define VOCAB  32000
#define BATCH  4
#define SEQ    2048
#define MROWS  (BATCH*SEQ)   /* 8192 */
#define IGNORE_INDEX (-100)

#define BM 256
#define BN 256
#define BK 64
#define KT (HIDDEN / BK)                     /* 32 K-tiles */
#define NBLK ((MROWS/BM) * (VOCAB/BN))       /* 32 * 125 = 4000 */

typedef float floatx4 __attribute__((ext_vector_type(4)));
typedef short short8  __attribute__((ext_vector_type(8)));

__device__ __forceinline__ unsigned short f2bf(float f) {
    unsigned u = __float_as_uint(f);
    u += 0x7fffu + ((u >> 16) & 1u);   // round-to-nearest-even
    return (unsigned short)(u >> 16);
}

__device__ __forceinline__ unsigned pack2(float a, float b) {
    return (unsigned)f2bf(a) | ((unsigned)f2bf(b) << 16);
}

// fenced barrier: raw s_barrier (no compiler-inserted vmcnt/lgkm drain),
// with compiler memory fences so no LDS/global op migrates across it.
__device__ __forceinline__ void bar() {
    asm volatile("" ::: "memory");
    __builtin_amdgcn_s_barrier();
    asm volatile("" ::: "memory");
}

// ---- cast W [VOCAB, HIDDEN] fp32 -> bf16 ----------------------------------
__global__ void cast_w(const float* __restrict__ W, unsigned short* __restrict__ out) {
    const size_t g = (size_t)blockIdx.x * 256 + threadIdx.x;   // thread handles 8 elems
    const float4* src = (const float4*)(W + g * 8);
    float4 a = src[0];
    float4 b = src[1];
    uint4 pk;
    pk.x = pack2(a.x, a.y);
    pk.y = pack2(a.z, a.w);
    pk.z = pack2(b.x, b.y);
    pk.w = pack2(b.z, b.w);
    *(uint4*)(out + g * 8) = pk;
}

// ---- gather embed[ids] -> bf16 hidden [MROWS, HIDDEN] ---------------------
__global__ void gather_cast(const int* __restrict__ ids,
                            const float* __restrict__ embed,
                            unsigned short* __restrict__ out) {
    const int row = blockIdx.x;
    const int t   = threadIdx.x;       // 256 threads, 8 elems each: 2048/row
    const int e   = ids[row];
    const float4* src = (const float4*)(embed + (size_t)e * HIDDEN + t * 8);
    float4 a = src[0];
    float4 b = src[1];
    uint4 pk;
    pk.x = pack2(a.x, a.y);
    pk.y = pack2(a.z, a.w);
    pk.z = pack2(b.x, b.y);
    pk.w = pack2(b.z, b.w);
    *(uint4*)(out + (size_t)row * HIDDEN + t * 8) = pk;
}

// ---- GEMM: C[m][n] = sum_k A[m][k] * B[n][k]  (A=hidden bf16, B=W bf16) ---
// 256x256 tile, BK=64, 8 waves (2Mx4N), 512 threads, 128 KiB LDS.
// 8-phase-per-2-K-tiles schedule (T3+T4): per K-tile 4 phases of
// {ds_read quadrant, stage prefetch, s_barrier, setprio(1), 16 MFMA,
//  setprio(0), s_barrier}; single late vmcnt(0) at phase 4 (>=2 phases of
// latency cover for the prefetch issued at phases 1-2). Chunk-XOR LDS
// swizzle (involution on both staging source and ds_read) keeps bank
// aliasing at the free 2-way level. XCD-bijective grid swizzle (4000%8==0).
__global__ __launch_bounds__(512, 2)
void gemm_bt(const unsigned short* __restrict__ A,   // [MROWS, HIDDEN]
             const unsigned short* __restrict__ B,   // [VOCAB, HIDDEN]
             float* __restrict__ C)                  // [MROWS, VOCAB] at d_out+1
{
    __shared__ __attribute__((aligned(16))) char lds[131072];
    const int tid = threadIdx.x;
    const int w   = tid >> 6;       // wave 0..7
    const int l   = tid & 63;
    const int wm  = w >> 2;         // 0..1  (wave row-half: owns A half-tile wm)
    const int wn  = w & 3;          // 0..3  (wave 64-col slot: B half wn>>1)
    const int l15 = l & 15;
    const int l4  = l >> 4;
    const int xv  = l15 & 7;                   // row&7 for all fragment rows
    const int x0  = ((l4    ) ^ xv) * 16;      // swizzled chunk-byte, k-half 0
    const int x1  = ((l4 + 4) ^ xv) * 16;      // swizzled chunk-byte, k-half 1

    // XCD-aware bijective swizzle: consecutive hw blocks round-robin XCDs;
    // give each XCD a contiguous run of 500 logical tiles (M fastest ->
    // its 32 resident blocks share one 1MB B-panel, L2-hot).
    const int bid = blockIdx.x;
    const int swz = (bid & 7) * (NBLK / 8) + (bid >> 3);
    const int mBase = (swz & 31) * BM;       // 32 M-tiles
    const int nBase = (swz >> 5) * BN;       // 125 N-tiles

    // staging map: thread stages physical chunks p0 (segment 0) and p1
    // (segment 1) of each 16KB half-tile; chunk p holds global
    // (row = p>>3, col8 = (p&7) ^ (row&7))  -- involution swizzle.
    const int p0 = w * 64 + l;               // 0..511
    const int p1 = p0 + 512;                 // 512..1023
    const int r0 = p0 >> 3, c80 = (p0 & 7) ^ (r0 & 7);
    const int r1 = p1 >> 3, c81 = (p1 & 7) ^ (r1 & 7);

    const unsigned short* Ab = A + (size_t)mBase * HIDDEN;
    const unsigned short* Bb = B + (size_t)nBase * HIDDEN;

    floatx4 acc[8][4] = {};

#define STAGE_HALF(gb, h, lbase, kk) do {                                         \
    const unsigned short* _g0 = (gb) + (size_t)((h)*128 + r0) * HIDDEN + (kk) + c80*8; \
    const unsigned short* _g1 = (gb) + (size_t)((h)*128 + r1) * HIDDEN + (kk) + c81*8; \
    __builtin_amdgcn_global_load_lds(                                             \
        (const __attribute__((address_space(1))) void*)_g0,                       \
        (__attribute__((address_space(3))) void*)((lbase) + w*1024), 16, 0, 0);   \
    __builtin_amdgcn_global_load_lds(                                             \
        (const __attribute__((address_space(1))) void*)_g1,                       \
        (__attribute__((address_space(3))) void*)((lbase) + 8192 + w*1024), 16, 0, 0); \
} while (0)

    // ---- prologue: stage K-tile 0 into buffer 0, full drain, rendezvous
    STAGE_HALF(Ab, 0, lds,         0);
    STAGE_HALF(Ab, 1, lds + 16384, 0);
    STAGE_HALF(Bb, 0, lds + 32768, 0);
    STAGE_HALF(Bb, 1, lds + 49152, 0);
    asm volatile("s_waitcnt vmcnt(0)" ::: "memory");
    __builtin_amdgcn_s_barrier();
    asm volatile("" ::: "memory");

#define RD_A(qm) do { _Pragma("unroll") for (int mt = 0; mt < 4; ++mt) {          \
    af[mt][0] = *(const short8*)(aP + (qm)*8192 + mt*2048 + x0);                  \
    af[mt][1] = *(const short8*)(aP + (qm)*8192 + mt*2048 + x1); } } while (0)
#define RD_B(qn) do { _Pragma("unroll") for (int nt = 0; nt < 2; ++nt) {          \
    bf[nt][0] = *(const short8*)(bP + (qn)*4096 + nt*2048 + x0);                  \
    bf[nt][1] = *(const short8*)(bP + (qn)*4096 + nt*2048 + x1); } } while (0)
#define MM(qm, qn) do {                                                           \
    _Pragma("unroll") for (int mt = 0; mt < 4; ++mt)                              \
    _Pragma("unroll") for (int nt = 0; nt < 2; ++nt)                              \
    _Pragma("unroll") for (int kh = 0; kh < 2; ++kh)                              \
        acc[(qm)*4+mt][(qn)*2+nt] = __builtin_amdgcn_mfma_f32_16x16x32_bf16(      \
            af[mt][kh], bf[nt][kh], acc[(qm)*4+mt][(qn)*2+nt], 0, 0, 0); } while (0)

#pragma unroll 2
    for (int u = 0; u < KT; ++u) {
        const int d = u & 1;
        const char* aP = lds + d*65536 + wm*16384 + l15*128;
        const char* bP = lds + d*65536 + 32768 + (wn>>1)*16384 + (wn&1)*8192 + l15*128;
        char* nb = lds + (d^1)*65536;
        const int  kk = (u + 1) * BK;
        const bool pf = (u + 1 < KT);
        short8 af[4][2], bf[2][2];

        // phase 1: quadrant (0,0); prefetch next A0,B0 (earliest legal point:
        // previous occupant of buffer d^1 fully read by last closing barrier)
        RD_A(0); RD_B(0);
        if (pf) { STAGE_HALF(Ab, 0, nb, kk); STAGE_HALF(Bb, 0, nb + 32768, kk); }
        bar();
        __builtin_amdgcn_s_setprio(1); MM(0,0); __builtin_amdgcn_s_setprio(0);
        bar();

        // phase 2: quadrant (1,0); prefetch next A1,B1 (B-frags reused)
        RD_A(1);
        if (pf) { STAGE_HALF(Ab, 1, nb + 16384, kk); STAGE_HALF(Bb, 1, nb + 49152, kk); }
        bar();
        __builtin_amdgcn_s_setprio(1); MM(1,0); __builtin_amdgcn_s_setprio(0);
        bar();

        // phase 3: quadrant (1,1)  (A-frags reused)
        RD_B(1);
        bar();
        __builtin_amdgcn_s_setprio(1); MM(1,1); __builtin_amdgcn_s_setprio(0);
        bar();

        // phase 4: quadrant (0,1)  (B-frags reused); late drain of the
        // prefetch issued >=2 phases ago, then rendezvous -> next tile reads
        RD_A(0);
        bar();
        __builtin_amdgcn_s_setprio(1); MM(0,1); __builtin_amdgcn_s_setprio(0);
        asm volatile("s_waitcnt vmcnt(0)" ::: "memory");
        bar();
    }

    // ---- epilogue: C/D layout col=lane&15, row=(lane>>4)*4+reg
    const int rq = l4 * 4;
    const int cc = l15;
#pragma unroll
    for (int i = 0; i < 8; ++i) {
        const int rowb = mBase + wm*128 + (i >> 2)*64 + (i & 3)*16 + rq;
#pragma unroll
        for (int j = 0; j < 4; ++j) {
            float* cp = C + (size_t)rowb * VOCAB
                          + nBase + wn*64 + (j >> 1)*32 + (j & 1)*16 + cc;
            floatx4 v = acc[i][j];
            cp[0 * (size_t)VOCAB] = v[0];
            cp[1 * (size_t)VOCAB] = v[1];
            cp[2 * (size_t)VOCAB] = v[2];
            cp[3 * (size_t)VOCAB] = v[3];
        }
    }
}

// ---- per-row online logsumexp + NLL --------------------------------------
__global__ void loss_kernel(const float* __restrict__ logits,  // d_out+1
                            const int* __restrict__ labels,
                            float* __restrict__ accum) {
    const int r = blockIdx.x;                    // 0..MROWS-1
    if ((r & (SEQ - 1)) == (SEQ - 1)) return;    // last position per batch: not used
    const int lab = labels[r + 1];
    if (lab == IGNORE_INDEX) return;
    const float* row = logits + (size_t)r * VOCAB;

    float m = -INFINITY, s = 0.0f;
    for (int i = threadIdx.x; i < VOCAB; i += 256) {   // 125 iters exactly
        float x  = row[i];
        float nm = fmaxf(m, x);
        s = s * __expf(m - nm) + __expf(x - nm);
        m = nm;
    }
#pragma unroll
    for (int off = 32; off > 0; off >>= 1) {
        float om = __shfl_xor(m, off, 64);
        float os = __shfl_xor(s, off, 64);
        float nm = fmaxf(m, om);
        s = s * __expf(m - nm) + os * __expf(om - nm);
        m = nm;
    }
    __shared__ float sm[4], ss[4];
    const int w = threadIdx.x >> 6, l = threadIdx.x & 63;
    if (l == 0) { sm[w] = m; ss[w] = s; }
    __syncthreads();
    if (threadIdx.x == 0) {
        float M = sm[0], S = ss[0];
#pragma unroll
        for (int i = 1; i < 4; ++i) {
            float nm = fmaxf(M, sm[i]);
            S = S * __expf(M - nm) + ss[i] * __expf(sm[i] - nm);
            M = nm;
        }
        float nll = (M + __logf(S)) - row[lab];
        atomicAdd(&accum[0], nll);
        atomicAdd(&accum[1], 1.0f);
    }
}

__global__ void finalize(const float* __restrict__ accum, float* __restrict__ out) {
    out[0] = accum[0] / fmaxf(accum[1], 1.0f);
}

extern "C" void kernel_launch(void* const* d_in, const int* in_sizes, int n_in,
                              void* d_out, int out_size, void* d_ws, size_t ws_size,
                              hipStream_t stream) {
    const int*   ids    = (const int*)d_in[0];
    const int*   labels = (const int*)d_in[1];
    const float* embed  = (const float*)d_in[2];
    const float* W      = (const float*)d_in[3];
    float* out = (float*)d_out;

    // workspace layout: W_bf16 (131072000 B) | hidden_bf16 (33554432 B) | accum (8 B)
    unsigned short* Wb = (unsigned short*)d_ws;
    unsigned short* Hb = (unsigned short*)((char*)d_ws + (size_t)VOCAB * HIDDEN * 2);
    float* accum = (float*)((char*)d_ws + (size_t)VOCAB * HIDDEN * 2 + (size_t)MROWS * HIDDEN * 2);

    hipMemsetAsync(accum, 0, 2 * sizeof(float), stream);
    cast_w<<<VOCAB * HIDDEN / (256 * 8), 256, 0, stream>>>(W, Wb);          // 32000 blocks
    gather_cast<<<MROWS, 256, 0, stream>>>(ids, embed, Hb);
    gemm_bt<<<NBLK, 512, 0, stream>>>(Hb, Wb, out + 1);
    loss_kernel<<<MROWS, 256, 0, stream>>>(out + 1, labels, accum);
    finalize<<<1, 1, 0, stream>>>(accum, out);
}